// Round 17
// baseline (261.869 us; speedup 1.0000x reference)
//
#include <hip/hip_runtime.h>
#include <hip/hip_bf16.h>
#include <math.h>

typedef __hip_bfloat16 bf16;
typedef __attribute__((ext_vector_type(8))) short bf16x8;
typedef __attribute__((ext_vector_type(4))) float f32x4;
typedef __attribute__((ext_vector_type(8))) int i32x8;
typedef __attribute__((ext_vector_type(4))) int i32x4;
typedef unsigned char u8;
typedef unsigned int u32;

#define T_SEQ   256
#define C_EMB   384
#define NH      6
#define HS      4
#define NB      128
#define NTOK    (NB * T_SEQ)   // 32768
#define VOC     65
#define FFDIM   1536
#define QKVW    72
#define PROJK   32
#define XROWS   (VOC * T_SEQ)  // 16640

#define X2_SCALE    128.0f
#define W1_SCALE    128.0f
#define FF1_DESCALE (1.0f / (128.0f * 128.0f))
#define H1_SCALE    512.0f
#define W2_SCALE    128.0f
#define FF2_DESCALE (1.0f / (512.0f * 128.0f))

__device__ __forceinline__ float b2f(bf16 x) { return __bfloat162float(x); }
__device__ __forceinline__ bf16  f2b(float x) { return __float2bfloat16(x); }
__device__ __forceinline__ short f2s(float x) { bf16 b = __float2bfloat16(x); return *reinterpret_cast<short*>(&b); }
__device__ __forceinline__ u8 f2fp8(float x) {
    return (u8)(__builtin_amdgcn_cvt_pk_fp8_f32(x, x, 0, false) & 0xff);
}
__device__ __forceinline__ u32 pk4fp8(const float* w) {
    int p = __builtin_amdgcn_cvt_pk_fp8_f32(w[0], w[1], 0, false);
    p = __builtin_amdgcn_cvt_pk_fp8_f32(w[2], w[3], p, true);
    return (u32)p;
}

// async 16B global->LDS. LDS dst = wave-uniform base + lane*16; global addr per-lane (gather ok).
__device__ __forceinline__ void glds16(const void* g, void* l) {
    __builtin_amdgcn_global_load_lds((const __attribute__((address_space(1))) void*)g,
                                     (__attribute__((address_space(3))) void*)l, 16, 0, 0);
}

__device__ __forceinline__ i32x8 ld_pair(const u8* rp, int off0, int off1) {
    i32x4 lo = *(const i32x4*)(rp + off0);
    i32x4 hi = *(const i32x4*)(rp + off1);
    i32x8 r;
    r[0]=lo[0]; r[1]=lo[1]; r[2]=lo[2]; r[3]=lo[3];
    r[4]=hi[0]; r[5]=hi[1]; r[6]=hi[2]; r[7]=hi[3];
    return r;
}

// ---------------- all weight packing + embedding table + loss-accumulator init, ONE dispatch
__global__ void pack_all_kernel(const float* __restrict__ Wq, const float* __restrict__ Wk,
                                const float* __restrict__ Wv, const float* __restrict__ Wlm,
                                const float* __restrict__ Wproj,
                                const float* __restrict__ W1, const float* __restrict__ W2,
                                const float* __restrict__ tok_emb, const float* __restrict__ pos_emb,
                                bf16* __restrict__ WqkvT, bf16* __restrict__ WlmT,
                                bf16* __restrict__ WprojT, u8* __restrict__ W1f8,
                                u8* __restrict__ W2f8, bf16* __restrict__ xtab,
                                float* __restrict__ lossbuf) {
    int blk = blockIdx.x;
    if (blk == 0 && threadIdx.x == 0) { lossbuf[0] = 0.f; ((int*)lossbuf)[1] = 0; }
    if (blk < 128) {                                   // WqkvT [128,384]
        int n = blk;
        for (int c = threadIdx.x; c < C_EMB; c += 256) {
            float v = 0.f;
            if (n < QKVW) {
                int sel = n / 24, r = n % 24, h = r >> 2, d = r & 3;
                const float* W = (sel == 0) ? Wq : (sel == 1) ? Wk : Wv;
                v = W[(h * C_EMB + c) * HS + d];
            }
            WqkvT[(size_t)n * C_EMB + c] = f2b(v);
        }
    } else if (blk < 256) {                            // WlmT [128,384]
        int n = blk - 128;
        for (int c = threadIdx.x; c < C_EMB; c += 256)
            WlmT[(size_t)n * C_EMB + c] = f2b(n < VOC ? Wlm[(size_t)c * VOC + n] : 0.f);
    } else if (blk < 640) {                            // WprojT [384,32]
        int n = blk - 256;
        int k = threadIdx.x;
        if (k < PROJK)
            WprojT[(size_t)n * PROJK + k] = f2b(k < 24 ? Wproj[(size_t)k * C_EMB + n] : 0.f);
    } else if (blk < 640 + FFDIM) {                    // W1f8 [1536,384] fp8 * W1_SCALE
        int n = blk - 640;
        for (int k = threadIdx.x; k < C_EMB; k += 256)
            W1f8[(size_t)n * C_EMB + k] = f2fp8(W1[(size_t)k * FFDIM + n] * W1_SCALE);
    } else if (blk < 640 + FFDIM + C_EMB) {            // W2f8 [384,1536] fp8 * W2_SCALE
        int n = blk - 640 - FFDIM;
        for (int k = threadIdx.x; k < FFDIM; k += 256)
            W2f8[(size_t)n * FFDIM + k] = f2fp8(W2[(size_t)k * C_EMB + n] * W2_SCALE);
    } else {                                           // xtab [65*256, 384] bf16
        int base = (blk - (640 + FFDIM + C_EMB)) * 4;
        for (int r = 0; r < 4; ++r) {
            int row = base + r;
            int id = row >> 8, t = row & 255;
            const float* te = tok_emb + (size_t)id * C_EMB;
            const float* pe = pos_emb + (size_t)t * C_EMB;
            bf16* dst = xtab + (size_t)row * C_EMB;
            for (int c = threadIdx.x; c < C_EMB; c += 256)
                dst[c] = f2b(te[c] + pe[c]);
        }
    }
}

// ---------------- QKV gather-GEMM, 512 threads / 8 waves
__global__ __launch_bounds__(512)
void qkv_gather_kernel(const int* __restrict__ idx, const bf16* __restrict__ xtab,
                       const bf16* __restrict__ Bt, float* __restrict__ outf) {
    __shared__ short As[128][32];
    __shared__ short Bs[128][32];
    __shared__ int rowid[128];
    int tid = threadIdx.x, lane = tid & 63, wave = tid >> 6;
    int bm = blockIdx.x * 128;
    int wm = (wave & 1) * 64, wn = (wave >> 1) * 32;
    int lrow = lane & 15, khalf = lane >> 4;
    if (tid < 128) { int token = bm + tid; rowid[tid] = idx[token] * T_SEQ + (token & (T_SEQ - 1)); }
    __syncthreads();

    int row = tid >> 2;
    int i0 = (tid & 3) * 16;
    int selem = ((i0 - ((row >> 1) & 3) * 16) & 63) >> 1;
    long ga = (long)rowid[row] * C_EMB;
    int arot = ((lrow >> 1) & 3) * 16;
    int roff = ((khalf * 16 + arot) & 63) >> 1;

    f32x4 acc[4][2] = {};
    for (int k0 = 0; k0 < C_EMB; k0 += 32) {
        glds16(xtab + ga + k0 + selem,                (short*)As + (size_t)tid * 8);
        glds16(Bt + (size_t)row * C_EMB + k0 + selem, (short*)Bs + (size_t)tid * 8);
        __syncthreads();

        bf16x8 af[4], bff[2];
        #pragma unroll
        for (int i = 0; i < 4; ++i)
            af[i] = *(const bf16x8*)&As[wm + i * 16 + lrow][roff];
        #pragma unroll
        for (int i = 0; i < 2; ++i)
            bff[i] = *(const bf16x8*)&Bs[wn + i * 16 + lrow][roff];
        #pragma unroll
        for (int mi = 0; mi < 4; ++mi)
            #pragma unroll
            for (int ni = 0; ni < 2; ++ni)
                acc[mi][ni] = __builtin_amdgcn_mfma_f32_16x16x32_bf16(af[mi], bff[ni], acc[mi][ni], 0, 0, 0);
        __syncthreads();
    }

    #pragma unroll
    for (int ni = 0; ni < 2; ++ni) {
        int col = wn + ni * 16 + lrow;
        if (col >= QKVW) continue;
        #pragma unroll
        for (int mi = 0; mi < 4; ++mi) {
            int orow = bm + wm + mi * 16 + khalf * 4;
            #pragma unroll
            for (int r = 0; r < 4; ++r)
                outf[(size_t)(orow + r) * QKVW + col] = acc[mi][ni][r];
        }
    }
}

// ---------------- causal softmax attention (online); writes bf16 attnT[token][32]
__global__ void attn_kernel(const float* __restrict__ qkv,
                            bf16* __restrict__ attnT) {
    int bh = blockIdx.x;
    int b = bh / NH, h = bh % NH;
    int t = threadIdx.x;
    __shared__ float ks[T_SEQ][HS];
    __shared__ float vs[T_SEQ][HS];
    const float* base = qkv + (size_t)(b * T_SEQ) * QKVW;
    #pragma unroll
    for (int d = 0; d < HS; ++d) {
        ks[t][d] = base[t * QKVW + 24 + h * HS + d];
        vs[t][d] = base[t * QKVW + 48 + h * HS + d];
    }
    __syncthreads();
    const float* qp = base + t * QKVW + h * HS;
    float q0 = qp[0], q1 = qp[1], q2 = qp[2], q3 = qp[3];
    const float scale = 0.05103103630798288f;   // 384^-0.5
    float m = -1e30f, sum = 0.f, o0 = 0.f, o1 = 0.f, o2 = 0.f, o3 = 0.f;
    for (int s = 0; s <= t; ++s) {
        float sc = (q0 * ks[s][0] + q1 * ks[s][1] + q2 * ks[s][2] + q3 * ks[s][3]) * scale;
        float mn = fmaxf(m, sc);
        float alpha = __expf(m - mn);
        float p = __expf(sc - mn);
        sum = sum * alpha + p;
        o0 = o0 * alpha + p * vs[s][0];
        o1 = o1 * alpha + p * vs[s][1];
        o2 = o2 * alpha + p * vs[s][2];
        o3 = o3 * alpha + p * vs[s][3];
        m = mn;
    }
    float inv = 1.f / sum;
    bf16* out = attnT + (size_t)(b * T_SEQ + t) * PROJK + h * HS;
    out[0] = f2b(o0 * inv); out[1] = f2b(o1 * inv); out[2] = f2b(o2 * inv); out[3] = f2b(o3 * inv);
    if (h == 0) {
        bf16* pad = attnT + (size_t)(b * T_SEQ + t) * PROJK + 24;
        *(uint4*)pad = uint4{0, 0, 0, 0};
    }
}

// ---------------- proj: MFMA bf16, BK=32, bank-swizzled; fp8 output (* oscale)
__global__ __launch_bounds__(256)
void gemm_mfma32_kernel(const bf16* __restrict__ A, const bf16* __restrict__ Bt,
                        const float* __restrict__ bias,
                        u8* __restrict__ outf8, float oscale,
                        int M, int K, int Nout) {
    __shared__ short As[128][32];
    __shared__ short Bs[128][32];
    int tid  = threadIdx.x;
    int lane = tid & 63;
    int wave = tid >> 6;
    int bm = blockIdx.y * 128;
    int bn = blockIdx.x * 128;
    int wm = (wave & 1) * 64;
    int wn = (wave >> 1) * 64;
    int lrow  = lane & 15;
    int khalf = lane >> 4;
    int arot = ((lrow >> 1) & 3) * 16;
    int roff = ((khalf * 16 + arot) & 63) >> 1;

    f32x4 acc[4][4] = {};
    for (int k0 = 0; k0 < K; k0 += 32) {
        #pragma unroll
        for (int h = 0; h < 2; ++h) {
            int c = tid + h * 256;
            int row = c >> 2;
            int i0 = (c & 3) * 16;
            int selem = ((i0 - ((row >> 1) & 3) * 16) & 63) >> 1;
            glds16(A  + (size_t)(bm + row) * K + k0 + selem, (short*)As + (size_t)c * 8);
            glds16(Bt + (size_t)(bn + row) * K + k0 + selem, (short*)Bs + (size_t)c * 8);
        }
        __syncthreads();

        bf16x8 af[4], bff[4];
        #pragma unroll
        for (int i = 0; i < 4; ++i) {
            af[i]  = *(const bf16x8*)&As[wm + i * 16 + lrow][roff];
            bff[i] = *(const bf16x8*)&Bs[wn + i * 16 + lrow][roff];
        }
        #pragma unroll
        for (int mi = 0; mi < 4; ++mi)
            #pragma unroll
            for (int ni = 0; ni < 4; ++ni)
                acc[mi][ni] = __builtin_amdgcn_mfma_f32_16x16x32_bf16(af[mi], bff[ni], acc[mi][ni], 0, 0, 0);
        __syncthreads();
    }

    #pragma unroll
    for (int ni = 0; ni < 4; ++ni) {
        int col = bn + wn + ni * 16 + lrow;
        float bv = bias[col];
        #pragma unroll
        for (int mi = 0; mi < 4; ++mi) {
            int row = bm + wm + mi * 16 + khalf * 4;
            float w[4];
            #pragma unroll
            for (int r = 0; r < 4; ++r) w[r] = (acc[mi][ni][r] + bv) * oscale;
            int p01 = __builtin_amdgcn_cvt_pk_fp8_f32(w[0], w[1], 0, false);
            int p23 = __builtin_amdgcn_cvt_pk_fp8_f32(w[2], w[3], 0, false);
            outf8[(size_t)(row + 0) * Nout + col] = (u8)(p01 & 0xff);
            outf8[(size_t)(row + 1) * Nout + col] = (u8)((p01 >> 8) & 0xff);
            outf8[(size_t)(row + 2) * Nout + col] = (u8)(p23 & 0xff);
            outf8[(size_t)(row + 3) * Nout + col] = (u8)((p23 >> 8) & 0xff);
        }
    }
}

// ---------------- fp8 MX MFMA GEMM, BM=128 x BN=128, BK=128, 512 threads.
// A staged in LDS (16 KB, rotated); B fragments loaded DIRECT from global (L2-resident
// weights, loads independent of the barrier -> natural prefetch). Swapped operands +
// LDS-staged coalesced epilogue (overlays A buffer). XCD swizzle. M/128 % 8 == 0.
__global__ __launch_bounds__(512)
void gemm_fp8_kernel(const u8* __restrict__ A, const u8* __restrict__ Bt,
                     const float* __restrict__ bias,
                     bf16* __restrict__ outb, u8* __restrict__ outf8,
                     float descale, float oscale,
                     int M, int K, int Nout, int NT, int relu) {
    __shared__ u8 smem[32768];
    u8* As = smem;            // [128][128], rows rotated by (r&7)*16B
    int lin  = blockIdx.x;
    int xcd  = lin & 7;
    int loc  = lin >> 3;
    int nt   = loc % NT;
    int mloc = loc / NT;
    int MPX  = (M / 128) >> 3;
    int bm = (xcd * MPX + mloc) * 128;
    int bn = nt * 128;

    int tid  = threadIdx.x;
    int lane = tid & 63;
    int wave = tid >> 6;
    int wm = (wave & 1) * 64;
    int wn = (wave >> 1) * 32;
    int lrow  = lane & 15;
    int khalf = lane >> 4;

    f32x4 acc[4][2] = {};
    int arot = (lrow & 7) * 16;
    int off0 = (khalf * 32 + arot) & 127;
    int off1 = (off0 + 16) & 127;

    for (int k0 = 0; k0 < K; k0 += 128) {
        // stage A only: 16 KB, 2 chunks/thread
        #pragma unroll
        for (int g = 0; g < 2; ++g) {
            int c = tid + g * 512;
            int row = c >> 3;
            int i0 = (c & 7) * 16;
            int s0 = (i0 - (row & 7) * 16) & 127;
            glds16(A + (size_t)(bm + row) * K + k0 + s0, As + (size_t)c * 16);
        }
        // B fragments straight from global (independent of barrier)
        i32x8 b[2];
        #pragma unroll
        for (int i = 0; i < 2; ++i) {
            const u8* rp = Bt + (size_t)(bn + wn + i * 16 + lrow) * K + k0 + khalf * 32;
            i32x4 lo = *(const i32x4*)rp;
            i32x4 hi = *(const i32x4*)(rp + 16);
            b[i][0]=lo[0]; b[i][1]=lo[1]; b[i][2]=lo[2]; b[i][3]=lo[3];
            b[i][4]=hi[0]; b[i][5]=hi[1]; b[i][6]=hi[2]; b[i][7]=hi[3];
        }
        __syncthreads();

        i32x8 a[4];
        #pragma unroll
        for (int i = 0; i < 4; ++i)
            a[i] = ld_pair(As + (size_t)(wm + i * 16 + lrow) * 128, off0, off1);
        // swapped: lane holds 4 consecutive n at fixed m
        #pragma unroll
        for (int mi = 0; mi < 4; ++mi)
            #pragma unroll
            for (int ni = 0; ni < 2; ++ni)
                acc[mi][ni] = __builtin_amdgcn_mfma_scale_f32_16x16x128_f8f6f4(
                    b[ni], a[mi], acc[mi][ni], 0, 0,
                    0, 0x7f7f7f7f, 0, 0x7f7f7f7f);
        __syncthreads();
    }

    // staged epilogue: pack per-lane 4n values -> LDS (rotated), then coalesced stores
    if (outf8) {
        #pragma unroll
        for (int mi = 0; mi < 4; ++mi) {
            int m = wm + mi * 16 + lrow;
            #pragma unroll
            for (int ni = 0; ni < 2; ++ni) {
                int n0 = wn + ni * 16 + khalf * 4;
                float4 bv = *(const float4*)(bias + bn + n0);
                float w[4];
                w[0] = acc[mi][ni][0] * descale + bv.x;
                w[1] = acc[mi][ni][1] * descale + bv.y;
                w[2] = acc[mi][ni][2] * descale + bv.z;
                w[3] = acc[mi][ni][3] * descale + bv.w;
                if (relu) {
                    w[0] = fmaxf(w[0], 0.f); w[1] = fmaxf(w[1], 0.f);
                    w[2] = fmaxf(w[2], 0.f); w[3] = fmaxf(w[3], 0.f);
                }
                w[0] *= oscale; w[1] *= oscale; w[2] *= oscale; w[3] *= oscale;
                *(u32*)&smem[(size_t)m * 128 + ((n0 + (m & 7) * 16) & 127)] = pk4fp8(w);
            }
        }
        __syncthreads();
        #pragma unroll
        for (int p = 0; p < 2; ++p) {
            int c = tid + p * 512;
            int row = c >> 3;
            int g0 = (c & 7) * 16;
            uint4 v = *(const uint4*)&smem[(size_t)row * 128 + ((g0 + (row & 7) * 16) & 127)];
            *(uint4*)&outf8[(size_t)(bm + row) * Nout + bn + g0] = v;
        }
    } else {
        short* Es = (short*)smem;   // [128] rows x 256B, rotated by (r&7)*16B
        #pragma unroll
        for (int mi = 0; mi < 4; ++mi) {
            int m = wm + mi * 16 + lrow;
            #pragma unroll
            for (int ni = 0; ni < 2; ++ni) {
                int n0 = wn + ni * 16 + khalf * 4;
                float4 bv = *(const float4*)(bias + bn + n0);
                union { short s[4]; uint2 u; } pk;
                pk.s[0] = f2s(acc[mi][ni][0] * descale + bv.x);
                pk.s[1] = f2s(acc[mi][ni][1] * descale + bv.y);
                pk.s[2] = f2s(acc[mi][ni][2] * descale + bv.z);
                pk.s[3] = f2s(acc[mi][ni][3] * descale + bv.w);
                *(uint2*)&Es[(size_t)m * 128 + ((n0 + (m & 7) * 8) & 127)] = pk.u;
            }
        }
        __syncthreads();
        #pragma unroll
        for (int p = 0; p < 4; ++p) {
            int c = tid + p * 512;
            int row = c >> 4;
            int g0 = (c & 15) * 16;   // byte offset in 256B row
            uint4 v = *(const uint4*)&smem[(size_t)row * 256 + ((g0 + (row & 7) * 16) & 255)];
            *(uint4*)((u8*)outb + ((size_t)(bm + row) * Nout + bn) * 2 + g0) = v;
        }
    }
}

// ---------------- LM head + fused CE loss + grid-level loss finish (atomics)
__global__ __launch_bounds__(512)
void lm_loss_kernel(const bf16* __restrict__ A, const bf16* __restrict__ Bt,
                    const float* __restrict__ bias, const int* __restrict__ targets,
                    float* __restrict__ outf, float* __restrict__ lossbuf,
                    float* __restrict__ out_loss, int M, int K) {
    __shared__ short As[128][32];
    __shared__ short Bs[128][32];
    __shared__ float Ls[128][66];
    __shared__ float red[128];
    int tid  = threadIdx.x;
    int lane = tid & 63;
    int wave = tid >> 6;
    int bm = blockIdx.x * 128;
    int wm = (wave & 1) * 64;
    int wn = (wave >> 1) * 32;
    int lrow  = lane & 15;
    int khalf = lane >> 4;

    int row = tid >> 2;
    int i0 = (tid & 3) * 16;
    int selem = ((i0 - ((row >> 1) & 3) * 16) & 63) >> 1;
    int arot = ((lrow >> 1) & 3) * 16;
    int roff = ((khalf * 16 + arot) & 63) >> 1;

    f32x4 acc[4][2] = {};
    for (int k0 = 0; k0 < K; k0 += 32) {
        glds16(A  + (size_t)(bm + row) * K + k0 + selem, (short*)As + (size_t)tid * 8);
        glds16(Bt + (size_t)row * K + k0 + selem,        (short*)Bs + (size_t)tid * 8);
        __syncthreads();

        bf16x8 af[4], bff[2];
        #pragma unroll
        for (int i = 0; i < 4; ++i)
            af[i] = *(const bf16x8*)&As[wm + i * 16 + lrow][roff];
        #pragma unroll
        for (int i = 0; i < 2; ++i)
            bff[i] = *(const bf16x8*)&Bs[wn + i * 16 + lrow][roff];
        #pragma unroll
        for (int mi = 0; mi < 4; ++mi)
            #pragma unroll
            for (int ni = 0; ni < 2; ++ni)
                acc[mi][ni] = __builtin_amdgcn_mfma_f32_16x16x32_bf16(af[mi], bff[ni], acc[mi][ni], 0, 0, 0);
        __syncthreads();
    }

    #pragma unroll
    for (int ni = 0; ni < 2; ++ni) {
        int col = wn + ni * 16 + lrow;
        if (col >= VOC) continue;
        float bv = bias[col];
        #pragma unroll
        for (int mi = 0; mi < 4; ++mi) {
            int lr = wm + mi * 16 + khalf * 4;
            #pragma unroll
            for (int r = 0; r < 4; ++r) {
                float v = acc[mi][ni][r] + bv;
                outf[(size_t)(bm + lr + r) * VOC + col] = v;
                Ls[lr + r][col] = v;
            }
        }
    }
    __syncthreads();

    if (tid < 128) {
        int token = bm + tid;
        int tgt = targets[token];
        float m = -1e30f, s = 0.f;
        #pragma unroll 8
        for (int c = 0; c < VOC; ++c) {
            float v = Ls[tid][c];
            float mn = fmaxf(m, v);
            s = s * __expf(m - mn) + __expf(v - mn);
            m = mn;
        }
        red[tid] = m + logf(s) - Ls[tid][tgt];
    }
    __syncthreads();
    if (tid < 64) {
        float s = red[tid] + red[tid + 64];
        #pragma unroll
        for (int off = 32; off > 0; off >>= 1) s += __shfl_xor(s, off);
        if (tid == 0) {
            atomicAdd(&lossbuf[0], s);
            __threadfence();
            int done = atomicAdd(&((int*)lossbuf)[1], 1);
            if (done == (NTOK / 128) - 1) {     // last block
                __threadfence();
                float total = atomicAdd(&lossbuf[0], 0.0f);
                out_loss[0] = total / (float)NTOK;
            }
        }
    }
}

extern "C" void kernel_launch(void* const* d_in, const int* in_sizes, int n_in,
                              void* d_out, int out_size, void* d_ws, size_t ws_size,
                              hipStream_t stream) {
    const int*   idx     = (const int*)  d_in[0];
    const int*   targets = (const int*)  d_in[1];
    const float* tok_emb = (const float*)d_in[2];
    const float* pos_emb = (const float*)d_in[3];
    const float* Wq      = (const float*)d_in[4];
    const float* Wk      = (const float*)d_in[5];
    const float* Wv      = (const float*)d_in[6];
    const float* Wproj   = (const float*)d_in[7];
    const float* bproj   = (const float*)d_in[8];
    const float* W1      = (const float*)d_in[9];
    const float* b1      = (const float*)d_in[10];
    const float* W2      = (const float*)d_in[11];
    const float* b2      = (const float*)d_in[12];
    const float* Wlm     = (const float*)d_in[13];
    const float* blm     = (const float*)d_in[14];

    char* ws = (char*)d_ws;
    bf16*  WprojT = (bf16*) (ws + 0);                       // 24576 B
    float* qkvbuf = (float*)(ws + 25165824);                // 9437184 B
    bf16*  attnT  = (bf16*) (ws + 34603008);                // 2097152 B
    bf16*  xtab   = (bf16*) (ws + 37748736);                // 12779520 B
    u8*    h1f8   = (u8*)   (ws + 62914560);                // 50331648 B
    u8*    x2f8   = (u8*)   (ws + 113246208);               // 12582912 B
    bf16*  x3     = (bf16*) (ws + 163577856);               // 25165824 B
    float* lossbuf= (float*)(ws + 188743680);               // [0]=sum, [1]=counter
    u8*    W1f8   = (u8*)   (ws + 188874752);               // 589824 B
    u8*    W2f8   = (u8*)   (ws + 190054400);               // 589824 B
    bf16*  WqkvT  = (bf16*) (ws + 191234048);               // 98304 B
    bf16*  WlmT   = (bf16*) (ws + 191332352);               // 98304 B

    float* out_logits = (float*)d_out;                      // [32768*65] f32
    float* out_loss   = out_logits + (size_t)NTOK * VOC;    // [1]

    pack_all_kernel<<<640 + FFDIM + C_EMB + XROWS / 4, 256, 0, stream>>>(
        Wq, Wk, Wv, Wlm, Wproj, W1, W2, tok_emb, pos_emb,
        WqkvT, WlmT, WprojT, W1f8, W2f8, xtab, lossbuf);

    qkv_gather_kernel<<<NTOK / 128, 512, 0, stream>>>(idx, xtab, WqkvT, qkvbuf);
    attn_kernel<<<NB * NH, T_SEQ, 0, stream>>>(qkvbuf, attnT);

    // proj: [32768,32] @ [32,384] + bproj -> x2 fp8 (* X2_SCALE)
    gemm_mfma32_kernel<<<dim3(C_EMB / 128, NTOK / 128), 256, 0, stream>>>(attnT, WprojT, bproj,
                                                                          x2f8, X2_SCALE,
                                                                          NTOK, PROJK, C_EMB);
    // FF1: fp8 [32768,384] @ fp8 [384->1536] + b1, relu -> h1 fp8 (* H1_SCALE). NT=12.
    gemm_fp8_kernel<<<(NTOK / 128) * (FFDIM / 128), 512, 0, stream>>>(x2f8, W1f8, b1,
                                                                      nullptr, h1f8,
                                                                      FF1_DESCALE, H1_SCALE,
                                                                      NTOK, C_EMB, FFDIM, FFDIM / 128, 1);
    // FF2: fp8 [32768,1536] @ fp8 [1536->384] + b2 -> x3 bf16. NT=3.
    gemm_fp8_kernel<<<(NTOK / 128) * (C_EMB / 128), 512, 0, stream>>>(h1f8, W2f8, b2,
                                                                      x3, nullptr,
                                                                      FF2_DESCALE, 1.0f,
                                                                      NTOK, FFDIM, C_EMB, C_EMB / 128, 0);
    // LM head + fused loss + grid loss finish
    lm_loss_kernel<<<NTOK / 128, 512, 0, stream>>>(x3, WlmT, blm, targets,
                                                   out_logits, lossbuf, out_loss, NTOK, C_EMB);
}

// Round 18
// 236.067 us; speedup vs baseline: 1.1093x; 1.1093x over previous
//
#include <hip/hip_runtime.h>
#include <hip/hip_bf16.h>
#include <math.h>

typedef __hip_bfloat16 bf16;
typedef __attribute__((ext_vector_type(8))) short bf16x8;
typedef __attribute__((ext_vector_type(4))) float f32x4;
typedef __attribute__((ext_vector_type(8))) int i32x8;
typedef __attribute__((ext_vector_type(4))) int i32x4;
typedef unsigned char u8;
typedef unsigned int u32;

#define T_SEQ   256
#define C_EMB   384
#define NH      6
#define HS      4
#define NB      128
#define NTOK    (NB * T_SEQ)   // 32768
#define VOC     65
#define FFDIM   1536
#define QKVW    72
#define PROJK   32
#define XROWS   (VOC * T_SEQ)  // 16640

#define X2_SCALE    128.0f
#define W1_SCALE    128.0f
#define FF1_DESCALE (1.0f / (128.0f * 128.0f))
#define H1_SCALE    512.0f
#define W2_SCALE    128.0f
#define FF2_DESCALE (1.0f / (512.0f * 128.0f))

__device__ __forceinline__ float b2f(bf16 x) { return __bfloat162float(x); }
__device__ __forceinline__ bf16  f2b(float x) { return __float2bfloat16(x); }
__device__ __forceinline__ short f2s(float x) { bf16 b = __float2bfloat16(x); return *reinterpret_cast<short*>(&b); }
__device__ __forceinline__ u8 f2fp8(float x) {
    return (u8)(__builtin_amdgcn_cvt_pk_fp8_f32(x, x, 0, false) & 0xff);
}
__device__ __forceinline__ u32 pk4fp8(const float* w) {
    int p = __builtin_amdgcn_cvt_pk_fp8_f32(w[0], w[1], 0, false);
    p = __builtin_amdgcn_cvt_pk_fp8_f32(w[2], w[3], p, true);
    return (u32)p;
}

// async 16B global->LDS. LDS dst = wave-uniform base + lane*16; global addr per-lane (gather ok).
__device__ __forceinline__ void glds16(const void* g, void* l) {
    __builtin_amdgcn_global_load_lds((const __attribute__((address_space(1))) void*)g,
                                     (__attribute__((address_space(3))) void*)l, 16, 0, 0);
}

// ---------------- all weight packing + embedding table + loss-accumulator init, ONE dispatch
__global__ void pack_all_kernel(const float* __restrict__ Wq, const float* __restrict__ Wk,
                                const float* __restrict__ Wv, const float* __restrict__ Wlm,
                                const float* __restrict__ Wproj,
                                const float* __restrict__ W1, const float* __restrict__ W2,
                                const float* __restrict__ tok_emb, const float* __restrict__ pos_emb,
                                bf16* __restrict__ WqkvT, bf16* __restrict__ WlmT,
                                bf16* __restrict__ WprojT, u8* __restrict__ W1f8,
                                u8* __restrict__ W2f8, bf16* __restrict__ xtab,
                                float* __restrict__ lossbuf) {
    int blk = blockIdx.x;
    if (blk == 0 && threadIdx.x == 0) { lossbuf[0] = 0.f; ((int*)lossbuf)[1] = 0; }
    if (blk < 128) {                                   // WqkvT [128,384]
        int n = blk;
        for (int c = threadIdx.x; c < C_EMB; c += 256) {
            float v = 0.f;
            if (n < QKVW) {
                int sel = n / 24, r = n % 24, h = r >> 2, d = r & 3;
                const float* W = (sel == 0) ? Wq : (sel == 1) ? Wk : Wv;
                v = W[(h * C_EMB + c) * HS + d];
            }
            WqkvT[(size_t)n * C_EMB + c] = f2b(v);
        }
    } else if (blk < 256) {                            // WlmT [128,384]
        int n = blk - 128;
        for (int c = threadIdx.x; c < C_EMB; c += 256)
            WlmT[(size_t)n * C_EMB + c] = f2b(n < VOC ? Wlm[(size_t)c * VOC + n] : 0.f);
    } else if (blk < 640) {                            // WprojT [384,32]
        int n = blk - 256;
        int k = threadIdx.x;
        if (k < PROJK)
            WprojT[(size_t)n * PROJK + k] = f2b(k < 24 ? Wproj[(size_t)k * C_EMB + n] : 0.f);
    } else if (blk < 640 + FFDIM) {                    // W1f8 [1536,384] fp8 * W1_SCALE
        int n = blk - 640;
        for (int k = threadIdx.x; k < C_EMB; k += 256)
            W1f8[(size_t)n * C_EMB + k] = f2fp8(W1[(size_t)k * FFDIM + n] * W1_SCALE);
    } else if (blk < 640 + FFDIM + C_EMB) {            // W2f8 [384,1536] fp8 * W2_SCALE
        int n = blk - 640 - FFDIM;
        for (int k = threadIdx.x; k < FFDIM; k += 256)
            W2f8[(size_t)n * FFDIM + k] = f2fp8(W2[(size_t)k * C_EMB + n] * W2_SCALE);
    } else {                                           // xtab [65*256, 384] bf16
        int base = (blk - (640 + FFDIM + C_EMB)) * 4;
        for (int r = 0; r < 4; ++r) {
            int row = base + r;
            int id = row >> 8, t = row & 255;
            const float* te = tok_emb + (size_t)id * C_EMB;
            const float* pe = pos_emb + (size_t)t * C_EMB;
            bf16* dst = xtab + (size_t)row * C_EMB;
            for (int c = threadIdx.x; c < C_EMB; c += 256)
                dst[c] = f2b(te[c] + pe[c]);
        }
    }
}

// ---------------- QKV gather-GEMM, 512 threads / 8 waves
__global__ __launch_bounds__(512)
void qkv_gather_kernel(const int* __restrict__ idx, const bf16* __restrict__ xtab,
                       const bf16* __restrict__ Bt, float* __restrict__ outf) {
    __shared__ short As[128][32];
    __shared__ short Bs[128][32];
    __shared__ int rowid[128];
    int tid = threadIdx.x, lane = tid & 63, wave = tid >> 6;
    int bm = blockIdx.x * 128;
    int wm = (wave & 1) * 64, wn = (wave >> 1) * 32;
    int lrow = lane & 15, khalf = lane >> 4;
    if (tid < 128) { int token = bm + tid; rowid[tid] = idx[token] * T_SEQ + (token & (T_SEQ - 1)); }
    __syncthreads();

    int row = tid >> 2;
    int i0 = (tid & 3) * 16;
    int selem = ((i0 - ((row >> 1) & 3) * 16) & 63) >> 1;
    long ga = (long)rowid[row] * C_EMB;
    int arot = ((lrow >> 1) & 3) * 16;
    int roff = ((khalf * 16 + arot) & 63) >> 1;

    f32x4 acc[4][2] = {};
    for (int k0 = 0; k0 < C_EMB; k0 += 32) {
        glds16(xtab + ga + k0 + selem,                (short*)As + (size_t)tid * 8);
        glds16(Bt + (size_t)row * C_EMB + k0 + selem, (short*)Bs + (size_t)tid * 8);
        __syncthreads();

        bf16x8 af[4], bff[2];
        #pragma unroll
        for (int i = 0; i < 4; ++i)
            af[i] = *(const bf16x8*)&As[wm + i * 16 + lrow][roff];
        #pragma unroll
        for (int i = 0; i < 2; ++i)
            bff[i] = *(const bf16x8*)&Bs[wn + i * 16 + lrow][roff];
        #pragma unroll
        for (int mi = 0; mi < 4; ++mi)
            #pragma unroll
            for (int ni = 0; ni < 2; ++ni)
                acc[mi][ni] = __builtin_amdgcn_mfma_f32_16x16x32_bf16(af[mi], bff[ni], acc[mi][ni], 0, 0, 0);
        __syncthreads();
    }

    #pragma unroll
    for (int ni = 0; ni < 2; ++ni) {
        int col = wn + ni * 16 + lrow;
        if (col >= QKVW) continue;
        #pragma unroll
        for (int mi = 0; mi < 4; ++mi) {
            int orow = bm + wm + mi * 16 + khalf * 4;
            #pragma unroll
            for (int r = 0; r < 4; ++r)
                outf[(size_t)(orow + r) * QKVW + col] = acc[mi][ni][r];
        }
    }
}

// ---------------- causal softmax attention (online); writes bf16 attnT[token][32]
__global__ void attn_kernel(const float* __restrict__ qkv,
                            bf16* __restrict__ attnT) {
    int bh = blockIdx.x;
    int b = bh / NH, h = bh % NH;
    int t = threadIdx.x;
    __shared__ float ks[T_SEQ][HS];
    __shared__ float vs[T_SEQ][HS];
    const float* base = qkv + (size_t)(b * T_SEQ) * QKVW;
    #pragma unroll
    for (int d = 0; d < HS; ++d) {
        ks[t][d] = base[t * QKVW + 24 + h * HS + d];
        vs[t][d] = base[t * QKVW + 48 + h * HS + d];
    }
    __syncthreads();
    const float* qp = base + t * QKVW + h * HS;
    float q0 = qp[0], q1 = qp[1], q2 = qp[2], q3 = qp[3];
    const float scale = 0.05103103630798288f;   // 384^-0.5
    float m = -1e30f, sum = 0.f, o0 = 0.f, o1 = 0.f, o2 = 0.f, o3 = 0.f;
    for (int s = 0; s <= t; ++s) {
        float sc = (q0 * ks[s][0] + q1 * ks[s][1] + q2 * ks[s][2] + q3 * ks[s][3]) * scale;
        float mn = fmaxf(m, sc);
        float alpha = __expf(m - mn);
        float p = __expf(sc - mn);
        sum = sum * alpha + p;
        o0 = o0 * alpha + p * vs[s][0];
        o1 = o1 * alpha + p * vs[s][1];
        o2 = o2 * alpha + p * vs[s][2];
        o3 = o3 * alpha + p * vs[s][3];
        m = mn;
    }
    float inv = 1.f / sum;
    bf16* out = attnT + (size_t)(b * T_SEQ + t) * PROJK + h * HS;
    out[0] = f2b(o0 * inv); out[1] = f2b(o1 * inv); out[2] = f2b(o2 * inv); out[3] = f2b(o3 * inv);
    if (h == 0) {
        bf16* pad = attnT + (size_t)(b * T_SEQ + t) * PROJK + 24;
        *(uint4*)pad = uint4{0, 0, 0, 0};
    }
}

// ---------------- proj: MFMA bf16, BK=32, bank-swizzled; fp8 output (* oscale)
__global__ __launch_bounds__(256)
void gemm_mfma32_kernel(const bf16* __restrict__ A, const bf16* __restrict__ Bt,
                        const float* __restrict__ bias,
                        u8* __restrict__ outf8, float oscale,
                        int M, int K, int Nout) {
    __shared__ short As[128][32];
    __shared__ short Bs[128][32];
    int tid  = threadIdx.x;
    int lane = tid & 63;
    int wave = tid >> 6;
    int bm = blockIdx.y * 128;
    int bn = blockIdx.x * 128;
    int wm = (wave & 1) * 64;
    int wn = (wave >> 1) * 64;
    int lrow  = lane & 15;
    int khalf = lane >> 4;
    int arot = ((lrow >> 1) & 3) * 16;
    int roff = ((khalf * 16 + arot) & 63) >> 1;

    f32x4 acc[4][4] = {};
    for (int k0 = 0; k0 < K; k0 += 32) {
        #pragma unroll
        for (int h = 0; h < 2; ++h) {
            int c = tid + h * 256;
            int row = c >> 2;
            int i0 = (c & 3) * 16;
            int selem = ((i0 - ((row >> 1) & 3) * 16) & 63) >> 1;
            glds16(A  + (size_t)(bm + row) * K + k0 + selem, (short*)As + (size_t)c * 8);
            glds16(Bt + (size_t)(bn + row) * K + k0 + selem, (short*)Bs + (size_t)c * 8);
        }
        __syncthreads();

        bf16x8 af[4], bff[4];
        #pragma unroll
        for (int i = 0; i < 4; ++i) {
            af[i]  = *(const bf16x8*)&As[wm + i * 16 + lrow][roff];
            bff[i] = *(const bf16x8*)&Bs[wn + i * 16 + lrow][roff];
        }
        #pragma unroll
        for (int mi = 0; mi < 4; ++mi)
            #pragma unroll
            for (int ni = 0; ni < 4; ++ni)
                acc[mi][ni] = __builtin_amdgcn_mfma_f32_16x16x32_bf16(af[mi], bff[ni], acc[mi][ni], 0, 0, 0);
        __syncthreads();
    }

    #pragma unroll
    for (int ni = 0; ni < 4; ++ni) {
        int col = bn + wn + ni * 16 + lrow;
        float bv = bias[col];
        #pragma unroll
        for (int mi = 0; mi < 4; ++mi) {
            int row = bm + wm + mi * 16 + khalf * 4;
            float w[4];
            #pragma unroll
            for (int r = 0; r < 4; ++r) w[r] = (acc[mi][ni][r] + bv) * oscale;
            int p01 = __builtin_amdgcn_cvt_pk_fp8_f32(w[0], w[1], 0, false);
            int p23 = __builtin_amdgcn_cvt_pk_fp8_f32(w[2], w[3], 0, false);
            outf8[(size_t)(row + 0) * Nout + col] = (u8)(p01 & 0xff);
            outf8[(size_t)(row + 1) * Nout + col] = (u8)((p01 >> 8) & 0xff);
            outf8[(size_t)(row + 2) * Nout + col] = (u8)(p23 & 0xff);
            outf8[(size_t)(row + 3) * Nout + col] = (u8)((p23 >> 8) & 0xff);
        }
    }
}

// ---------------- unified fp8 MX-scaled MFMA GEMM, BK=128, 512 threads, bank-swizzled,
// XCD-aware block swizzle; SWAPPED operands + LDS-staged coalesced epilogue. (R15 form — best)
__global__ __launch_bounds__(512)
void gemm_fp8_kernel(const u8* __restrict__ A, const u8* __restrict__ Bt,
                     const float* __restrict__ bias,
                     bf16* __restrict__ outb, u8* __restrict__ outf8,
                     float descale, float oscale,
                     int M, int K, int Nout, int NT, int relu) {
    __shared__ u8 smem[32768];
    u8* As = smem;            // [128][128], rows rotated by (r&7)*16B
    u8* Bs = smem + 16384;
    int lin  = blockIdx.x;
    int xcd  = lin & 7;
    int loc  = lin >> 3;
    int nt   = loc % NT;
    int mloc = loc / NT;
    int MPX  = (M / 128) >> 3;
    int bm = (xcd * MPX + mloc) * 128;
    int bn = nt * 128;

    int tid  = threadIdx.x;
    int lane = tid & 63;
    int wave = tid >> 6;
    int wm = (wave & 1) * 64;
    int wn = (wave >> 1) * 32;
    int lrow  = lane & 15;
    int khalf = lane >> 4;

    f32x4 acc[4][2] = {};
    int r0 = tid >> 3;
    int i0 = (tid & 7) * 16;
    int s0 = (i0 - (r0 & 7) * 16) & 127;
    int arot = (lrow & 7) * 16;
    int off0 = (khalf * 32 + arot) & 127;
    int off1 = (off0 + 16) & 127;

    for (int k0 = 0; k0 < K; k0 += 128) {
        const u8* Ag = A  + (size_t)(bm + r0) * K + k0 + s0;
        const u8* Bg = Bt + (size_t)(bn + r0) * K + k0 + s0;
        glds16(Ag,                  As + (size_t)tid * 16);
        glds16(Ag + (size_t)64 * K, As + 8192 + (size_t)tid * 16);
        glds16(Bg,                  Bs + (size_t)tid * 16);
        glds16(Bg + (size_t)64 * K, Bs + 8192 + (size_t)tid * 16);
        __syncthreads();

        i32x8 a[4], b[2];
        #pragma unroll
        for (int i = 0; i < 4; ++i) {
            const u8* rp = As + (size_t)(wm + i * 16 + lrow) * 128;
            i32x4 lo = *(const i32x4*)(rp + off0);
            i32x4 hi = *(const i32x4*)(rp + off1);
            a[i][0]=lo[0]; a[i][1]=lo[1]; a[i][2]=lo[2]; a[i][3]=lo[3];
            a[i][4]=hi[0]; a[i][5]=hi[1]; a[i][6]=hi[2]; a[i][7]=hi[3];
        }
        #pragma unroll
        for (int i = 0; i < 2; ++i) {
            const u8* rp = Bs + (size_t)(wn + i * 16 + lrow) * 128;
            i32x4 lo = *(const i32x4*)(rp + off0);
            i32x4 hi = *(const i32x4*)(rp + off1);
            b[i][0]=lo[0]; b[i][1]=lo[1]; b[i][2]=lo[2]; b[i][3]=lo[3];
            b[i][4]=hi[0]; b[i][5]=hi[1]; b[i][6]=hi[2]; b[i][7]=hi[3];
        }
        // swapped: lane holds 4 consecutive n at fixed m
        #pragma unroll
        for (int mi = 0; mi < 4; ++mi)
            #pragma unroll
            for (int ni = 0; ni < 2; ++ni)
                acc[mi][ni] = __builtin_amdgcn_mfma_scale_f32_16x16x128_f8f6f4(
                    b[ni], a[mi], acc[mi][ni], 0, 0,
                    0, 0x7f7f7f7f, 0, 0x7f7f7f7f);
        __syncthreads();
    }

    // staged epilogue: pack per-lane 4n values -> LDS (rotated), then coalesced stores
    if (outf8) {
        #pragma unroll
        for (int mi = 0; mi < 4; ++mi) {
            int m = wm + mi * 16 + lrow;
            #pragma unroll
            for (int ni = 0; ni < 2; ++ni) {
                int n0 = wn + ni * 16 + khalf * 4;
                float4 bv = *(const float4*)(bias + bn + n0);
                float w[4];
                w[0] = acc[mi][ni][0] * descale + bv.x;
                w[1] = acc[mi][ni][1] * descale + bv.y;
                w[2] = acc[mi][ni][2] * descale + bv.z;
                w[3] = acc[mi][ni][3] * descale + bv.w;
                if (relu) {
                    w[0] = fmaxf(w[0], 0.f); w[1] = fmaxf(w[1], 0.f);
                    w[2] = fmaxf(w[2], 0.f); w[3] = fmaxf(w[3], 0.f);
                }
                w[0] *= oscale; w[1] *= oscale; w[2] *= oscale; w[3] *= oscale;
                *(u32*)&smem[(size_t)m * 128 + ((n0 + (m & 7) * 16) & 127)] = pk4fp8(w);
            }
        }
        __syncthreads();
        #pragma unroll
        for (int p = 0; p < 2; ++p) {
            int c = tid + p * 512;
            int row = c >> 3;
            int g0 = (c & 7) * 16;
            uint4 v = *(const uint4*)&smem[(size_t)row * 128 + ((g0 + (row & 7) * 16) & 127)];
            *(uint4*)&outf8[(size_t)(bm + row) * Nout + bn + g0] = v;
        }
    } else {
        short* Es = (short*)smem;   // [128][128] shorts = 32 KB, rows rotated by (r&7)*16B
        #pragma unroll
        for (int mi = 0; mi < 4; ++mi) {
            int m = wm + mi * 16 + lrow;
            #pragma unroll
            for (int ni = 0; ni < 2; ++ni) {
                int n0 = wn + ni * 16 + khalf * 4;
                float4 bv = *(const float4*)(bias + bn + n0);
                union { short s[4]; uint2 u; } pk;
                pk.s[0] = f2s(acc[mi][ni][0] * descale + bv.x);
                pk.s[1] = f2s(acc[mi][ni][1] * descale + bv.y);
                pk.s[2] = f2s(acc[mi][ni][2] * descale + bv.z);
                pk.s[3] = f2s(acc[mi][ni][3] * descale + bv.w);
                *(uint2*)&Es[(size_t)m * 128 + ((n0 + (m & 7) * 8) & 127)] = pk.u;
            }
        }
        __syncthreads();
        #pragma unroll
        for (int p = 0; p < 4; ++p) {
            int c = tid + p * 512;
            int row = c >> 4;
            int g0 = (c & 15) * 16;   // byte offset in 256B row
            uint4 v = *(const uint4*)&smem[(size_t)row * 256 + ((g0 + (row & 7) * 16) & 255)];
            *(uint4*)((u8*)outb + ((size_t)(bm + row) * Nout + bn) * 2 + g0) = v;
        }
    }
}

// ---------------- LM head + fused CE loss + grid-level loss finish (atomics)
__global__ __launch_bounds__(512)
void lm_loss_kernel(const bf16* __restrict__ A, const bf16* __restrict__ Bt,
                    const float* __restrict__ bias, const int* __restrict__ targets,
                    float* __restrict__ outf, float* __restrict__ lossbuf,
                    float* __restrict__ out_loss, int M, int K) {
    __shared__ short As[128][32];
    __shared__ short Bs[128][32];
    __shared__ float Ls[128][66];
    __shared__ float red[128];
    int tid  = threadIdx.x;
    int lane = tid & 63;
    int wave = tid >> 6;
    int bm = blockIdx.x * 128;
    int wm = (wave & 1) * 64;
    int wn = (wave >> 1) * 32;
    int lrow  = lane & 15;
    int khalf = lane >> 4;

    int row = tid >> 2;
    int i0 = (tid & 3) * 16;
    int selem = ((i0 - ((row >> 1) & 3) * 16) & 63) >> 1;
    int arot = ((lrow >> 1) & 3) * 16;
    int roff = ((khalf * 16 + arot) & 63) >> 1;

    f32x4 acc[4][2] = {};
    for (int k0 = 0; k0 < K; k0 += 32) {
        glds16(A  + (size_t)(bm + row) * K + k0 + selem, (short*)As + (size_t)tid * 8);
        glds16(Bt + (size_t)row * K + k0 + selem,        (short*)Bs + (size_t)tid * 8);
        __syncthreads();

        bf16x8 af[4], bff[2];
        #pragma unroll
        for (int i = 0; i < 4; ++i)
            af[i] = *(const bf16x8*)&As[wm + i * 16 + lrow][roff];
        #pragma unroll
        for (int i = 0; i < 2; ++i)
            bff[i] = *(const bf16x8*)&Bs[wn + i * 16 + lrow][roff];
        #pragma unroll
        for (int mi = 0; mi < 4; ++mi)
            #pragma unroll
            for (int ni = 0; ni < 2; ++ni)
                acc[mi][ni] = __builtin_amdgcn_mfma_f32_16x16x32_bf16(af[mi], bff[ni], acc[mi][ni], 0, 0, 0);
        __syncthreads();
    }

    #pragma unroll
    for (int ni = 0; ni < 2; ++ni) {
        int col = wn + ni * 16 + lrow;
        if (col >= VOC) continue;
        float bv = bias[col];
        #pragma unroll
        for (int mi = 0; mi < 4; ++mi) {
            int lr = wm + mi * 16 + khalf * 4;
            #pragma unroll
            for (int r = 0; r < 4; ++r) {
                float v = acc[mi][ni][r] + bv;
                outf[(size_t)(bm + lr + r) * VOC + col] = v;
                Ls[lr + r][col] = v;
            }
        }
    }
    __syncthreads();

    if (tid < 128) {
        int token = bm + tid;
        int tgt = targets[token];
        float m = -1e30f, s = 0.f;
        #pragma unroll 8
        for (int c = 0; c < VOC; ++c) {
            float v = Ls[tid][c];
            float mn = fmaxf(m, v);
            s = s * __expf(m - mn) + __expf(v - mn);
            m = mn;
        }
        red[tid] = m + logf(s) - Ls[tid][tgt];
    }
    __syncthreads();
    if (tid < 64) {
        float s = red[tid] + red[tid + 64];
        #pragma unroll
        for (int off = 32; off > 0; off >>= 1) s += __shfl_xor(s, off);
        if (tid == 0) {
            atomicAdd(&lossbuf[0], s);
            __threadfence();
            int done = atomicAdd(&((int*)lossbuf)[1], 1);
            if (done == (NTOK / 128) - 1) {     // last block
                __threadfence();
                float total = atomicAdd(&lossbuf[0], 0.0f);
                out_loss[0] = total / (float)NTOK;
            }
        }
    }
}

extern "C" void kernel_launch(void* const* d_in, const int* in_sizes, int n_in,
                              void* d_out, int out_size, void* d_ws, size_t ws_size,
                              hipStream_t stream) {
    const int*   idx     = (const int*)  d_in[0];
    const int*   targets = (const int*)  d_in[1];
    const float* tok_emb = (const float*)d_in[2];
    const float* pos_emb = (const float*)d_in[3];
    const float* Wq      = (const float*)d_in[4];
    const float* Wk      = (const float*)d_in[5];
    const float* Wv      = (const float*)d_in[6];
    const float* Wproj   = (const float*)d_in[7];
    const float* bproj   = (const float*)d_in[8];
    const float* W1      = (const float*)d_in[9];
    const float* b1      = (const float*)d_in[10];
    const float* W2      = (const float*)d_in[11];
    const float* b2      = (const float*)d_in[12];
    const float* Wlm     = (const float*)d_in[13];
    const float* blm     = (const float*)d_in[14];

    char* ws = (char*)d_ws;
    bf16*  WprojT = (bf16*) (ws + 0);                       // 24576 B
    float* qkvbuf = (float*)(ws + 25165824);                // 9437184 B
    bf16*  attnT  = (bf16*) (ws + 34603008);                // 2097152 B
    bf16*  xtab   = (bf16*) (ws + 37748736);                // 12779520 B
    u8*    h1f8   = (u8*)   (ws + 62914560);                // 50331648 B
    u8*    x2f8   = (u8*)   (ws + 113246208);               // 12582912 B
    bf16*  x3     = (bf16*) (ws + 163577856);               // 25165824 B
    float* lossbuf= (float*)(ws + 188743680);               // [0]=sum, [1]=counter
    u8*    W1f8   = (u8*)   (ws + 188874752);               // 589824 B
    u8*    W2f8   = (u8*)   (ws + 190054400);               // 589824 B
    bf16*  WqkvT  = (bf16*) (ws + 191234048);               // 98304 B
    bf16*  WlmT   = (bf16*) (ws + 191332352);               // 98304 B

    float* out_logits = (float*)d_out;                      // [32768*65] f32
    float* out_loss   = out_logits + (size_t)NTOK * VOC;    // [1]

    pack_all_kernel<<<640 + FFDIM + C_EMB + XROWS / 4, 256, 0, stream>>>(
        Wq, Wk, Wv, Wlm, Wproj, W1, W2, tok_emb, pos_emb,
        WqkvT, WlmT, WprojT, W1f8, W2f8, xtab, lossbuf);

    qkv_gather_kernel<<<NTOK / 128, 512, 0, stream>>>(idx, xtab, WqkvT, qkvbuf);
    attn_kernel<<<NB * NH, T_SEQ, 0, stream>>>(qkvbuf, attnT);

    // proj: [32768,32] @ [32,384] + bproj -> x2 fp8 (* X2_SCALE)
    gemm_mfma32_kernel<<<dim3(C_EMB / 128, NTOK / 128), 256, 0, stream>>>(attnT, WprojT, bproj,
                                                                          x2f8, X2_SCALE,
                                                                          NTOK, PROJK, C_EMB);
    // FF1: fp8 [32768,384] @ fp8 [384->1536] + b1, relu -> h1 fp8 (* H1_SCALE). NT=12.
    gemm_fp8_kernel<<<(NTOK / 128) * (FFDIM / 128), 512, 0, stream>>>(x2f8, W1f8, b1,
                                                                      nullptr, h1f8,
                                                                      FF1_DESCALE, H1_SCALE,
                                                                      NTOK, C_EMB, FFDIM, FFDIM / 128, 1);
    // FF2: fp8 [32768,1536] @ fp8 [1536->384] + b2 -> x3 bf16. NT=3.
    gemm_fp8_kernel<<<(NTOK / 128) * (C_EMB / 128), 512, 0, stream>>>(h1f8, W2f8, b2,
                                                                      x3, nullptr,
                                                                      FF2_DESCALE, 1.0f,
                                                                      NTOK, FFDIM, C_EMB, C_EMB / 128, 0);
    // LM head + fused loss + grid loss finish
    lm_loss_kernel<<<NTOK / 128, 512, 0, stream>>>(x3, WlmT, blm, targets,
                                                   out_logits, lossbuf, out_loss, NTOK, C_EMB);
}